// Round 7
// baseline (62.097 us; speedup 1.0000x reference)
//
#include <hip/hip_runtime.h>

// NEmbedding: out[b,f,e] = relu( sum_n enc[b,f,n] * W[f,n,e] + bias[f,e] )
// enc[n] = (x - bins[n]) * g[n] for all n except the containing bin k, where
// enc[k] = 1.  => out = relu( x*P[f,e] + R[f,e] + c * W[f,k,e] ),
// c = (hi_k - x)/(hi_k - lo_k),  P = sum_n g_n W_n,  R = bias - sum_n lo_n g_n W_n,
// k = largest n with bins[f,n] <= x (0 if none).
//
// R1/R2: load-before-store batching (106 -> 64 us). R3: vmcnt-FIFO theory dead
// (neutral). R4: plain stores ~= nt stores; prep restructure -2.4 us (61.6).
// R5: wave-autonomous structure. No __syncthreads after bins staging: each
//     wave owns 4 b-rows end-to-end (lane-local x -> search -> wave-private
//     LDS patch -> s_waitcnt lgkmcnt(0) -> 32x1KB coalesced stores). Removes
//     the 2-barriers-per-tile convoys that stall all 4 waves of a block
//     together and gap the store pipe (fill kernel: barrier-free, 6.9 TB/s at
//     10% occupancy). Patch writes swizzled (+8u mod 64) to avoid 8-way LDS
//     write conflicts; P/R re-read per f-octet from L2 (coalesced, cheap).
// R6: resubmit of R5 verbatim — container infra failure, no bench signal.

#define FDIM 64
#define NB   64
#define EDIM 32

typedef __attribute__((ext_vector_type(4))) float f32x4;
typedef __attribute__((ext_vector_type(4))) int   i32x4;

__global__ __launch_bounds__(256) void prep_kernel(
    const float* __restrict__ bins, const float* __restrict__ W,
    const float* __restrict__ bias,
    float* __restrict__ P, float* __restrict__ R)
{
    const int f = blockIdx.x;
    const int t = threadIdx.x;
    __shared__ float sg[NB];
    __shared__ float sb[NB];
    __shared__ float redP[8][EDIM];
    __shared__ float redQ[8][EDIM];

    if (t < NB) {
        float lo = bins[f * NB + t];
        float hi = (t < NB - 1) ? bins[f * NB + t + 1] : -1.0f;
        sg[t] = 1.0f / (hi - lo);
        sb[t] = lo;
    }
    __syncthreads();

    const int e  = t & (EDIM - 1);
    const int ch = t >> 5;                    // 0..7, each owns 8 n's
    float p = 0.0f, q = 0.0f;
    const float* Wf = W + (size_t)f * NB * EDIM + e;
    #pragma unroll
    for (int i = 0; i < 8; ++i) {
        int n = ch * 8 + i;
        float w = Wf[n * EDIM];
        p = fmaf(sg[n], w, p);
        q = fmaf(sb[n] * sg[n], w, q);
    }
    redP[ch][e] = p;
    redQ[ch][e] = q;
    __syncthreads();

    if (t < EDIM) {
        float P_ = 0.0f, Q_ = 0.0f;
        #pragma unroll
        for (int c = 0; c < 8; ++c) { P_ += redP[c][t]; Q_ += redQ[c][t]; }
        P[f * EDIM + t] = P_;
        R[f * EDIM + t] = bias[f * EDIM + t] - Q_;
    }
}

__global__ __launch_bounds__(256) void nemb_kernel(
    const float* __restrict__ x, const float* __restrict__ bins,
    const float* __restrict__ W,
    const float* __restrict__ P, const float* __restrict__ R,
    float* __restrict__ out)
{
    // bins rows padded to 65 floats; [64] = -1.0 sentinel (hi of last bin).
    __shared__ float sBins[FDIM * (NB + 1)];
    __shared__ float sX[16 * 64];   // 4 rows x 64 f per wave, 4 waves
    __shared__ float sC[16 * 64];
    __shared__ int   sK[16 * 64];

    const int t = threadIdx.x;

    // ---- stage bins + sentinel (the ONLY block-wide sync) ----
    #pragma unroll
    for (int i = 0; i < 4; ++i) {
        int li = i * 256 + t;                 // float4 index
        f32x4 v = reinterpret_cast<const f32x4*>(bins)[li];
        int el = li * 4;
        int f = el >> 6, n = el & 63;         // n % 4 == 0, no row crossing
        float* d = &sBins[f * (NB + 1) + n];
        d[0] = v.x; d[1] = v.y; d[2] = v.z; d[3] = v.w;
    }
    if (t < FDIM) sBins[t * (NB + 1) + NB] = -1.0f;
    __syncthreads();

    // ---- wave-autonomous from here: wave w owns rows 4g..4g+3 ----
    const int w  = t >> 6;
    const int l  = t & 63;
    const int u  = l >> 4;                    // 0..3: row within group
    const int m  = l & 15;                    // f-quad index
    const int d8 = l >> 3;                    // 0..7
    const int e0 = (l & 7) * 4;
    const long g = (long)blockIdx.x * 4 + w;  // group id; rows 4g..4g+3
    const int prow = w * 4;                   // this wave's LDS patch rows

    // lane-local x: row 4g+u, features 4m..4m+3 (1 KB/wave, coalesced)
    f32x4 x4 = __builtin_nontemporal_load(
        reinterpret_cast<const f32x4*>(x + (4 * g + u) * FDIM + 4 * m));

    // 4 independent binary searches (ILP=4)
    float cc[4]; int kk[4];
    #pragma unroll
    for (int j = 0; j < 4; ++j) {
        const float* bl = &sBins[(4 * m + j) * (NB + 1)];
        float xv = x4[j];
        int k = (bl[32] <= xv) ? 32 : 0;
        if (bl[k + 16] <= xv) k += 16;
        if (bl[k +  8] <= xv) k +=  8;
        if (bl[k +  4] <= xv) k +=  4;
        if (bl[k +  2] <= xv) k +=  2;
        if (bl[k +  1] <= xv) k +=  1;
        float lo = bl[k];
        float hi = bl[k + 1];                 // k=63 -> sentinel -1.0
        cc[j] = (hi - xv) * __builtin_amdgcn_rcpf(hi - lo);
        kk[j] = k;
    }

    // write wave-private patch; +8u mod 64 swizzle de-conflicts the b128
    // writes (u would otherwise not move the bank index)
    {
        int wbase = (prow + u) * 64 + ((4 * m + 8 * u) & 63);
        *reinterpret_cast<f32x4*>(&sX[wbase]) = x4;
        f32x4 cv4; cv4.x = cc[0]; cv4.y = cc[1]; cv4.z = cc[2]; cv4.w = cc[3];
        *reinterpret_cast<f32x4*>(&sC[wbase]) = cv4;
        i32x4 kv4; kv4.x = kk[0]; kv4.y = kk[1]; kv4.z = kk[2]; kv4.w = kk[3];
        *reinterpret_cast<i32x4*>(&sK[wbase]) = kv4;
    }
    // per-wave DS completion: our own writes are visible to our own reads
    asm volatile("s_waitcnt lgkmcnt(0)" ::: "memory");

    // ---- store loop: 32 x 1KB fully coalesced, no syncs ----
    float* og = out + (4 * g) * (FDIM * EDIM);
    #pragma unroll
    for (int i = 0; i < 8; ++i) {
        const int fi = 8 * i + d8;
        f32x4 Pv = *reinterpret_cast<const f32x4*>(P + fi * EDIM + e0);
        f32x4 Rv = *reinterpret_cast<const f32x4*>(R + fi * EDIM + e0);
        #pragma unroll
        for (int r = 0; r < 4; ++r) {
            int idx = (prow + r) * 64 + ((fi + 8 * r) & 63);
            float xv = sX[idx];               // broadcast reads (8 lanes/addr)
            float cv = sC[idx];
            int   kv = sK[idx];
            f32x4 Wv = *reinterpret_cast<const f32x4*>(
                W + ((fi * NB + kv) * EDIM) + e0);
            f32x4 o;
            o.x = fmaxf(fmaf(cv, Wv.x, fmaf(xv, Pv.x, Rv.x)), 0.0f);
            o.y = fmaxf(fmaf(cv, Wv.y, fmaf(xv, Pv.y, Rv.y)), 0.0f);
            o.z = fmaxf(fmaf(cv, Wv.z, fmaf(xv, Pv.z, Rv.z)), 0.0f);
            o.w = fmaxf(fmaf(cv, Wv.w, fmaf(xv, Pv.w, Rv.w)), 0.0f);
            *reinterpret_cast<f32x4*>(og + (long)r * (FDIM * EDIM)
                                      + fi * EDIM + e0) = o;
        }
    }
}

extern "C" void kernel_launch(void* const* d_in, const int* in_sizes, int n_in,
                              void* d_out, int out_size, void* d_ws, size_t ws_size,
                              hipStream_t stream) {
    const float* x    = (const float*)d_in[0];   // (B, F)
    const float* bins = (const float*)d_in[1];   // (F, NB) sorted rows
    const float* W    = (const float*)d_in[2];   // (F, NB, E)
    const float* bias = (const float*)d_in[3];   // (F, E)
    float* out = (float*)d_out;

    // workspace layout: P (F*E) | R (F*E)  -> 16 KB total
    float* P = (float*)d_ws;
    float* R = P + FDIM * EDIM;

    const int B = in_sizes[0] / FDIM;            // rows; groups of 4 per wave

    prep_kernel<<<FDIM, 256, 0, stream>>>(bins, W, bias, P, R);
    nemb_kernel<<<B / 16, 256, 0, stream>>>(x, bins, W, P, R, out);
}

// Round 8
// 59.351 us; speedup vs baseline: 1.0463x; 1.0463x over previous
//
#include <hip/hip_runtime.h>

// NEmbedding: out[b,f,e] = relu( x*P[f,e] + R[f,e] + c * W[f,k,e] ),
// c = (hi_k - x)/(hi_k - lo_k),  P = sum_n g_n W_n,  R = bias - sum_n lo_n g_n W_n,
// k = largest n with bins[f,n] <= x (0 if none); hi of last bin = -1.0.
//
// R1-R4: load-before-store batching (106->64), nt-stores neutral, pipelining
// neutral, prep restructure (-2.4 -> 61.6). R5/R6: barrier-free wave-autonomous
// structure NEUTRAL (62.1) -> convoy theory dead.
// R7: kill the data-dependent W gather against the write-thrashed L2 (each
//     XCD streams 32MB through its 4MB L2 per replay -> W can't stay
//     resident; ~200MB of scattered refetch + exposed miss latency inside the
//     store stream; also explains why nt-store A/B was neutral). Blocks are
//     f-sliced: 8 features x 256 rows; the 64KB W-slice is LDS-staged once
//     (rows padded to 33 floats -> <=2-way banks) and every per-output W read
//     is an LDS read. slice = blockIdx&7 -> XCD-affine W staging. No barriers
//     after staging; wave-private patch + lgkmcnt(0) as in R5.

#define FDIM 64
#define NB   64
#define EDIM 32
#define FSL  8      // features per slice
#define NRPB 256    // rows per block
#define WPAD 33     // padded W row (floats)

typedef __attribute__((ext_vector_type(4))) float f32x4;

__global__ __launch_bounds__(256) void prep_kernel(
    const float* __restrict__ bins, const float* __restrict__ W,
    const float* __restrict__ bias,
    float* __restrict__ P, float* __restrict__ R)
{
    const int f = blockIdx.x;
    const int t = threadIdx.x;
    __shared__ float sg[NB];
    __shared__ float sb[NB];
    __shared__ float redP[8][EDIM];
    __shared__ float redQ[8][EDIM];

    if (t < NB) {
        float lo = bins[f * NB + t];
        float hi = (t < NB - 1) ? bins[f * NB + t + 1] : -1.0f;
        sg[t] = 1.0f / (hi - lo);
        sb[t] = lo;
    }
    __syncthreads();

    const int e  = t & (EDIM - 1);
    const int ch = t >> 5;                    // 0..7, each owns 8 n's
    float p = 0.0f, q = 0.0f;
    const float* Wf = W + (size_t)f * NB * EDIM + e;
    #pragma unroll
    for (int i = 0; i < 8; ++i) {
        int n = ch * 8 + i;
        float w = Wf[n * EDIM];
        p = fmaf(sg[n], w, p);
        q = fmaf(sb[n] * sg[n], w, q);
    }
    redP[ch][e] = p;
    redQ[ch][e] = q;
    __syncthreads();

    if (t < EDIM) {
        float P_ = 0.0f, Q_ = 0.0f;
        #pragma unroll
        for (int c = 0; c < 8; ++c) { P_ += redP[c][t]; Q_ += redQ[c][t]; }
        P[f * EDIM + t] = P_;
        R[f * EDIM + t] = bias[f * EDIM + t] - Q_;
    }
}

__global__ __launch_bounds__(256) void nemb_kernel(
    const float* __restrict__ x, const float* __restrict__ bins,
    const float* __restrict__ W,
    const float* __restrict__ P, const float* __restrict__ R,
    float* __restrict__ out)
{
    __shared__ float sW[FSL * NB * WPAD];     // 67.6 KB, padded rows
    __shared__ float sBins[FSL * 65];         // 65th = -1.0 sentinel
    __shared__ float pX[4][64];               // per-wave patches [w][row*8+f]
    __shared__ float pC[4][64];
    __shared__ int   pK[4][64];

    const int t     = threadIdx.x;
    const int slice = blockIdx.x & 7;         // -> XCD-affine under %8 dispatch
    const int chunk = blockIdx.x >> 3;
    const int f0    = slice * FSL;

    // ---- stage W slice (64 KB) into padded LDS ----
    const float* Wg = W + (size_t)f0 * NB * EDIM;
    #pragma unroll
    for (int i = 0; i < 16; ++i) {
        int qi = i * 256 + t;                 // f32x4 index within slice
        f32x4 v = reinterpret_cast<const f32x4*>(Wg)[qi];
        int gi = qi * 4;
        int fl = gi >> 11;                    // 0..7
        int n  = (gi >> 5) & 63;
        int e0 = gi & 31;                     // multiple of 4
        *reinterpret_cast<f32x4*>(&sW[fl * (NB * WPAD) + n * WPAD + e0]) = v;
    }
    // ---- stage bins slice + sentinels ----
    if (t < 128) {
        f32x4 v = reinterpret_cast<const f32x4*>(bins + f0 * NB)[t];
        int gi = t * 4;
        int fl = gi >> 6, n = gi & 63;
        float* d = &sBins[fl * 65 + n];
        d[0] = v.x; d[1] = v.y; d[2] = v.z; d[3] = v.w;
    }
    if (t < FSL) sBins[t * 65 + 64] = -1.0f;
    __syncthreads();                          // the only block-wide sync

    // ---- wave-autonomous: wave w owns rows {rb..rb+7} per iteration ----
    const int w  = t >> 6;
    const int l  = t & 63;
    const int rs = l >> 3;                    // search: row-in-8
    const int fs = l & 7;                     // search: f-in-slice
    const int ft = l >> 3;                    // store: f-in-slice
    const int e0 = (l & 7) * 4;               // store: e-quad

    // hoisted P/R for the store mapping (fixed per lane)
    const f32x4 Pv = *reinterpret_cast<const f32x4*>(P + (f0 + ft) * EDIM + e0);
    const f32x4 Rv = *reinterpret_cast<const f32x4*>(R + (f0 + ft) * EDIM + e0);

    const long r00 = (long)chunk * NRPB;

    #pragma unroll 2
    for (int it = 0; it < NRPB / 32; ++it) {
        const long rb = r00 + it * 32 + w * 8;

        // search for (row rb+rs, feature f0+fs); 8-lane-contiguous x reads
        float xv = x[(rb + rs) * FDIM + f0 + fs];
        const float* bl = &sBins[fs * 65];
        int k = (bl[32] <= xv) ? 32 : 0;
        if (bl[k + 16] <= xv) k += 16;
        if (bl[k +  8] <= xv) k +=  8;
        if (bl[k +  4] <= xv) k +=  4;
        if (bl[k +  2] <= xv) k +=  2;
        if (bl[k +  1] <= xv) k +=  1;
        float lo = bl[k];
        float hi = bl[k + 1];                 // k=63 -> sentinel -1.0
        float cv = (hi - xv) * __builtin_amdgcn_rcpf(hi - lo);

        pX[w][rs * 8 + fs] = xv;
        pC[w][rs * 8 + fs] = cv;
        pK[w][rs * 8 + fs] = k;
        // per-wave DS drain; patch is wave-private so no barrier needed
        asm volatile("s_waitcnt lgkmcnt(0)" ::: "memory");

        // 8 rows x 1KB fully coalesced stores; W from LDS only
        #pragma unroll
        for (int r = 0; r < 8; ++r) {
            float xr = pX[w][r * 8 + ft];     // 8-lane broadcast reads
            float cr = pC[w][r * 8 + ft];
            int   kr = pK[w][r * 8 + ft];
            f32x4 Wv = *reinterpret_cast<const f32x4*>(
                &sW[ft * (NB * WPAD) + kr * WPAD + e0]);
            f32x4 o;
            o.x = fmaxf(fmaf(cr, Wv.x, fmaf(xr, Pv.x, Rv.x)), 0.0f);
            o.y = fmaxf(fmaf(cr, Wv.y, fmaf(xr, Pv.y, Rv.y)), 0.0f);
            o.z = fmaxf(fmaf(cr, Wv.z, fmaf(xr, Pv.z, Rv.z)), 0.0f);
            o.w = fmaxf(fmaf(cr, Wv.w, fmaf(xr, Pv.w, Rv.w)), 0.0f);
            *reinterpret_cast<f32x4*>(
                out + (rb + r) * (FDIM * EDIM) + (f0 + ft) * EDIM + e0) = o;
        }
    }
}

extern "C" void kernel_launch(void* const* d_in, const int* in_sizes, int n_in,
                              void* d_out, int out_size, void* d_ws, size_t ws_size,
                              hipStream_t stream) {
    const float* x    = (const float*)d_in[0];   // (B, F)
    const float* bins = (const float*)d_in[1];   // (F, NB) sorted rows
    const float* W    = (const float*)d_in[2];   // (F, NB, E)
    const float* bias = (const float*)d_in[3];   // (F, E)
    float* out = (float*)d_out;

    // workspace layout: P (F*E) | R (F*E)  -> 16 KB total
    float* P = (float*)d_ws;
    float* R = P + FDIM * EDIM;

    const int B = in_sizes[0] / FDIM;            // 32768
    const int nchunks = B / NRPB;                // 128

    prep_kernel<<<FDIM, 256, 0, stream>>>(bins, W, bias, P, R);
    nemb_kernel<<<nchunks * 8, 256, 0, stream>>>(x, bins, W, P, R, out);
}